// Round 1
// 195.253 us; speedup vs baseline: 1.0556x; 1.0556x over previous
//
#include <hip/hip_runtime.h>
#include <math.h>

#define SPB 3136      // spatial positions per batch (56*56)
#define NB 8
#define MTOT (NB*SPB) // 25088 = 196*128, flattened M across batch
#define EPS 1e-5f

typedef unsigned short u16;
typedef __attribute__((ext_vector_type(8))) short short8;
typedef __attribute__((ext_vector_type(4))) float float4v;

__device__ __forceinline__ float b2f(u16 v){ unsigned u=((unsigned)v)<<16; float f; __builtin_memcpy(&f,&u,4); return f; }
__device__ __forceinline__ u16 f2b(float f){ unsigned u; __builtin_memcpy(&u,&f,4); u += 0x7fffu + ((u>>16)&1u); return (u16)(u>>16); }
// tanh-approx GELU via sigmoid: gelu(z) ~= z * sigmoid(1.5957691216*z*(1+0.044715*z^2))
// max abs error vs exact-erf gelu ~1e-3, well under bf16 rounding already present.
__device__ __forceinline__ float gelu_f(float z){
  float t = 1.5957691216f * z * (1.0f + 0.044715f*z*z);
  return __fdividef(z, 1.0f + __expf(-t));
}

// async global->LDS, 16B per lane; lds dest must be wave-uniform base + lane*16
__device__ __forceinline__ void gll16(const u16* g, u16* l){
  __builtin_amdgcn_global_load_lds((const __attribute__((address_space(1))) void*)g,
                                   (__attribute__((address_space(3))) void*)l, 16, 0, 0);
}

// ---- fold BN constants: s = g/sqrt(v+eps), t = b*s + be - m*s ----
// cst layout: s1[256] t1[256] sg[512] tg[512] s2[256] t2[256]
__global__ void prep_consts_k(const float* b1,const float* g1,const float* be1,const float* m1,const float* v1,
                              const float* bg,const float* gg,const float* beg,const float* mg,const float* vg,
                              const float* b2,const float* g2,const float* be2,const float* m2,const float* v2,
                              float* cst){
  int i = threadIdx.x;
  if (i < 256) {
    float s = g1[i]*rsqrtf(v1[i]+EPS);
    cst[i] = s; cst[256+i] = b1[i]*s + be1[i] - m1[i]*s;
    float s2 = g2[i]*rsqrtf(v2[i]+EPS);
    cst[1536+i] = s2; cst[1792+i] = b2[i]*s2 + be2[i] - m2[i]*s2;
  }
  float s = gg[i]*rsqrtf(vg[i]+EPS);
  cst[512+i] = s; cst[1024+i] = bg[i]*s + beg[i] - mg[i]*s;
}

__global__ void conv_w_k(const float* __restrict__ w1,const float* __restrict__ wg,const float* __restrict__ w2,
                         u16* __restrict__ w1b,u16* __restrict__ wgb,u16* __restrict__ w2b){
  int i = blockIdx.x*256 + threadIdx.x;
  if (i < 65536)  w1b[i] = f2b(w1[i]);
  if (i < 262144) wgb[i] = f2b(wg[i]);
  if (i < 131072) w2b[i] = f2b(w2[i]);
}

// x [b][c][s] fp32 -> xt [b][s][c] bf16
__global__ void transpose_x_k(const float* __restrict__ x, u16* __restrict__ xt){
  __shared__ float t[32][33];
  int b = blockIdx.z, ct = blockIdx.y, st = blockIdx.x;
  int ts = threadIdx.x, tc = threadIdx.y;
  #pragma unroll
  for (int i=0;i<4;i++){
    int c = tc + i*8;
    t[c][ts] = x[((size_t)(b*256 + ct*32 + c))*SPB + st*32 + ts];
  }
  __syncthreads();
  #pragma unroll
  for (int i=0;i<4;i++){
    int r = tc + i*8;
    xt[((size_t)(b*SPB + st*32 + r))*256 + ct*32 + ts] = f2b(t[ts][r]);
  }
}

// per (b,y): min over x of h, split by x-parity.  h = cat[...,0:256]
__global__ void rowmin_k(const u16* __restrict__ cat, float* __restrict__ rmin){
  int b = blockIdx.x/56, y = blockIdx.x%56, c = threadIdx.x;
  float mE=3.4e38f, mO=3.4e38f;
  const u16* base = cat + ((size_t)(b*SPB + y*56))*512 + c;
  for (int x=0;x<56;x+=2){
    mE = fminf(mE, b2f(base[(size_t)x*512]));
    mO = fminf(mO, b2f(base[(size_t)(x+1)*512]));
  }
  rmin[((size_t)(b*2+0)*56 + y)*256 + c]=mE;
  rmin[((size_t)(b*2+1)*56 + y)*256 + c]=mO;
}
// per (b,x): min over y of h, split by y-parity
__global__ void colmin_k(const u16* __restrict__ cat, float* __restrict__ cmin){
  int b = blockIdx.x/56, x = blockIdx.x%56, c = threadIdx.x;
  float mE=3.4e38f, mO=3.4e38f;
  const u16* base = cat + ((size_t)(b*SPB + x))*512 + c;
  for (int y=0;y<56;y+=2){
    mE = fminf(mE, b2f(base[(size_t)(y*56)*512]));
    mO = fminf(mO, b2f(base[(size_t)((y+1)*56)*512]));
  }
  cmin[((size_t)(b*2+0)*56 + x)*256 + c]=mE;
  cmin[((size_t)(b*2+1)*56 + x)*256 + c]=mO;
}
// xj = max(0, h - min(colMinP[y%2][x], rowMinP[x%2][y])) -> cat[...,256:512]
__global__ void xj_k(u16* __restrict__ cat, const float* __restrict__ rmin, const float* __restrict__ cmin){
  int b = blockIdx.y, s = blockIdx.x, c = threadIdx.x;
  int y = s/56, x = s%56;
  size_t idx = ((size_t)(b*SPB + s))*512;
  float h = b2f(cat[idx + c]);
  float m = fminf(cmin[((size_t)(b*2+(y&1))*56 + x)*256 + c],
                  rmin[((size_t)(b*2+(x&1))*56 + y)*256 + c]);
  cat[idx + 256 + c] = f2b(fmaxf(0.0f, h - m));
}

// GEMM: D[m][o] = sum_k Ain[m][k] * Wt[o][k]; M flattened over batch.
// Tiles BM=128(m) x BN=128(o) x BK=32; 4 waves, each 64x64 (4x4 MFMA tiles).
// DOUBLE-BUFFERED staging (T3 minimum 2-phase): STAGE(t+1) issued before
// COMPUTE(t); the single __syncthreads per iteration (vmcnt(0)+barrier)
// lands AFTER the MFMAs, so global->LDS latency hides under compute.
// LDS: 2 buffers x (As 8KB + Bs 8KB) = 32KB, unioned with epilogue tile
// (32KB for EPI1/2, 33792B for EPI3) -> block LDS unchanged at 33792B.
// EPI 1: bf16( acc*s + t )              -> out [m][512] at col o0
// EPI 2: bf16( gelu(acc*s + t) )        -> out [m][512] at col o0
// EPI 3: fp32( acc*s + t + x[b][o][s] ) -> out [b][256][s]
template<int KTOT, int EPI>
__global__ __launch_bounds__(256) void gemm_k(
    const u16* __restrict__ Ain, const u16* __restrict__ Wt,
    const float* __restrict__ scale, const float* __restrict__ bias,
    void* __restrict__ outp, const float* __restrict__ resid)
{
  __shared__ __align__(16) u16 smem[16896];   // 33792 B (union: dbuf staging / epilogue)
  const int tid = threadIdx.x;
  const int m0 = blockIdx.x * 128;
  const int o0 = blockIdx.y * 128;
  const int lane = tid & 63, wid = tid >> 6;
  const int quad = lane >> 4, l16 = lane & 15;
  const int wm = wid & 1, wn = wid >> 1;

  float4v acc[4][4];
  #pragma unroll
  for (int i=0;i<4;i++)
    #pragma unroll
    for (int j=0;j<4;j++) acc[i][j] = (float4v){0.f,0.f,0.f,0.f};

  // staging: buffer buf at smem + buf*8192 (u16 units):
  //   As [128][32] at +0, Bs [128][32] at +4096.
  // chunk c in [0,512): row=c>>2, q=c&3; thread t handles chunks t and 256+t
  const int row = tid >> 2, q8 = (tid & 3) * 8;
  const u16* ga0 = Ain + ((size_t)(m0 + row))*KTOT + q8;
  const u16* ga1 = ga0 + (size_t)64*KTOT;
  const u16* gb0 = Wt  + ((size_t)(o0 + row))*KTOT + q8;
  const u16* gb1 = gb0 + (size_t)64*KTOT;
  u16* l8 = smem + tid*8;

  auto STAGE = [&](int kt, int buf){
    u16* b_ = l8 + buf*8192;
    gll16(ga0 + kt, b_);
    gll16(ga1 + kt, b_ + 2048);
    gll16(gb0 + kt, b_ + 4096);
    gll16(gb1 + kt, b_ + 6144);
  };
  auto COMPUTE = [&](int buf){
    const u16* A_ = smem + buf*8192;
    const u16* B_ = A_ + 4096;
    short8 af[4], bfr[4];
    #pragma unroll
    for (int im=0;im<4;im++) af[im]  = *(const short8*)&A_[(wm*64+im*16+l16)*32 + quad*8];
    #pragma unroll
    for (int in=0;in<4;in++) bfr[in] = *(const short8*)&B_[(wn*64+in*16+l16)*32 + quad*8];
    #pragma unroll
    for (int im=0;im<4;im++)
      #pragma unroll
      for (int in=0;in<4;in++)
        acc[im][in] = __builtin_amdgcn_mfma_f32_16x16x32_bf16(af[im], bfr[in], acc[im][in], 0, 0, 0);
  };

  constexpr int NIT = KTOT / 32;
  STAGE(0, 0);
  __syncthreads();            // drain prologue loads
  #pragma unroll
  for (int t = 1; t < NIT; ++t) {
    STAGE(t*32, t & 1);       // issue next tile's loads first...
    COMPUTE((t-1) & 1);       // ...then compute current; loads fly under MFMA
    __syncthreads();          // vmcnt(0)+barrier: next buffer ready, cur reads done
  }
  COMPUTE((NIT-1) & 1);
  __syncthreads();            // all waves done with staging buffers -> smem reuse ok

  if (EPI == 1 || EPI == 2) {
    u16* tile = smem; // [128 m][128 o]
    #pragma unroll
    for (int im=0;im<4;im++)
      #pragma unroll
      for (int in=0;in<4;in++){
        int ol = wn*64 + in*16 + l16;
        float sc = scale[o0+ol], bi = bias[o0+ol];
        #pragma unroll
        for (int r=0;r<4;r++){
          float v = acc[im][in][r]*sc + bi;
          if (EPI==2) v = gelu_f(v);
          tile[(wm*64+im*16+quad*4+r)*128 + ol] = f2b(v);
        }
      }
    __syncthreads();
    u16* op = (u16*)outp;
    #pragma unroll
    for (int p=0;p<8;p++){
      int chunk = p*256 + tid;
      int rr = chunk >> 4, off = (chunk & 15)*8;
      *(uint4*)&op[((size_t)(m0 + rr))*512 + o0 + off] = *(const uint4*)&tile[rr*128 + off];
    }
  } else {
    float* ftile = (float*)smem; // [64 o][132 m] padded, one 64-chan half at a time
    float* op = (float*)outp;
    #pragma unroll
    for (int h=0; h<2; h++){
      if (wn == h){
        #pragma unroll
        for (int im=0;im<4;im++)
          #pragma unroll
          for (int in=0;in<4;in++){
            int c64 = in*16 + l16;
            int og = o0 + h*64 + c64;
            float sc = scale[og], bi = bias[og];
            float4v v;
            #pragma unroll
            for (int r=0;r<4;r++) v[r] = acc[im][in][r]*sc + bi;
            *(float4v*)&ftile[c64*132 + wm*64 + im*16 + quad*4] = v;
          }
      }
      __syncthreads();
      #pragma unroll
      for (int p=0;p<8;p++){
        int chunk = p*256 + tid;
        int rr = chunk >> 5, off = (chunk & 31)*4;
        int m = m0 + off;
        int b = m / SPB, s = m - b*SPB;
        size_t g = ((size_t)(b*256 + o0 + h*64 + rr))*SPB + s;
        float4v v = *(const float4v*)&ftile[rr*132 + off];
        v.x += resid[g]; v.y += resid[g+1]; v.z += resid[g+2]; v.w += resid[g+3];
        *(float4v*)&op[g] = v;
      }
      __syncthreads();
    }
  }
}

extern "C" void kernel_launch(void* const* d_in, const int* in_sizes, int n_in,
                              void* d_out, int out_size, void* d_ws, size_t ws_size,
                              hipStream_t stream)
{
  const float* x  = (const float*)d_in[0];
  const float* w1 = (const float*)d_in[1];
  const float* b1 = (const float*)d_in[2];
  const float* g1 = (const float*)d_in[3];
  const float* be1= (const float*)d_in[4];
  const float* m1 = (const float*)d_in[5];
  const float* v1 = (const float*)d_in[6];
  const float* wg = (const float*)d_in[7];
  const float* bg = (const float*)d_in[8];
  const float* gg = (const float*)d_in[9];
  const float* beg= (const float*)d_in[10];
  const float* mg = (const float*)d_in[11];
  const float* vg = (const float*)d_in[12];
  const float* w2 = (const float*)d_in[13];
  const float* b2 = (const float*)d_in[14];
  const float* g2 = (const float*)d_in[15];
  const float* be2= (const float*)d_in[16];
  const float* m2 = (const float*)d_in[17];
  const float* v2 = (const float*)d_in[18];

  char* ws = (char*)d_ws;
  size_t off = 0;
  auto alloc = [&](size_t bytes){ void* p = ws + off; off += (bytes + 255) & ~(size_t)255; return p; };
  u16* xt    = (u16*)alloc((size_t)MTOT*256*2);   // x transposed, bf16
  u16* catt  = (u16*)alloc((size_t)MTOT*512*2);   // [h ; xj] transposed, bf16
  u16* gt    = (u16*)alloc((size_t)MTOT*512*2);   // gelu output transposed, bf16
  u16* w1b   = (u16*)alloc((size_t)65536*2);
  u16* wgb   = (u16*)alloc((size_t)262144*2);
  u16* w2b   = (u16*)alloc((size_t)131072*2);
  float* cst = (float*)alloc((size_t)2048*4);
  float* rmin= (float*)alloc((size_t)NB*2*56*256*4);
  float* cmin= (float*)alloc((size_t)NB*2*56*256*4);

  hipLaunchKernelGGL(prep_consts_k, dim3(1), dim3(512), 0, stream,
                     b1,g1,be1,m1,v1, bg,gg,beg,mg,vg, b2,g2,be2,m2,v2, cst);
  hipLaunchKernelGGL(conv_w_k, dim3(1024), dim3(256), 0, stream, w1,wg,w2, w1b,wgb,w2b);
  hipLaunchKernelGGL(transpose_x_k, dim3(98,8,8), dim3(32,8), 0, stream, x, xt);
  hipLaunchKernelGGL((gemm_k<256,1>), dim3(196,2), dim3(256), 0, stream,
                     xt, w1b, cst+0, cst+256, (void*)catt, (const float*)nullptr);
  hipLaunchKernelGGL(rowmin_k, dim3(NB*56), dim3(256), 0, stream, catt, rmin);
  hipLaunchKernelGGL(colmin_k, dim3(NB*56), dim3(256), 0, stream, catt, cmin);
  hipLaunchKernelGGL(xj_k, dim3(SPB, NB), dim3(256), 0, stream, catt, rmin, cmin);
  hipLaunchKernelGGL((gemm_k<512,2>), dim3(196,4), dim3(256), 0, stream,
                     catt, wgb, cst+512, cst+1024, (void*)gt, (const float*)nullptr);
  hipLaunchKernelGGL((gemm_k<512,3>), dim3(196,2), dim3(256), 0, stream,
                     gt, w2b, cst+1536, cst+1792, d_out, x);
}

// Round 3
// 186.604 us; speedup vs baseline: 1.1045x; 1.0463x over previous
//
#include <hip/hip_runtime.h>
#include <math.h>

#define SPB 3136      // spatial positions per batch (56*56)
#define NB 8
#define MTOT (NB*SPB) // 25088 = 196*128, flattened M across batch
#define EPS 1e-5f

typedef unsigned short u16;
typedef __attribute__((ext_vector_type(8))) short short8;
typedef __attribute__((ext_vector_type(4))) float float4v;

__device__ __forceinline__ float b2f(u16 v){ unsigned u=((unsigned)v)<<16; float f; __builtin_memcpy(&f,&u,4); return f; }
__device__ __forceinline__ u16 f2b(float f){ unsigned u; __builtin_memcpy(&u,&f,4); u += 0x7fffu + ((u>>16)&1u); return (u16)(u>>16); }
// tanh-approx GELU via sigmoid: gelu(z) ~= z * sigmoid(1.5957691216*z*(1+0.044715*z^2))
// max abs error vs exact-erf gelu ~1e-3, well under bf16 rounding already present.
__device__ __forceinline__ float gelu_f(float z){
  float t = 1.5957691216f * z * (1.0f + 0.044715f*z*z);
  return __fdividef(z, 1.0f + __expf(-t));
}

// async global->LDS, 16B per lane; lds dest must be wave-uniform base + lane*16
__device__ __forceinline__ void gll16(const u16* g, u16* l){
  __builtin_amdgcn_global_load_lds((const __attribute__((address_space(1))) void*)g,
                                   (__attribute__((address_space(3))) void*)l, 16, 0, 0);
}

// ---- fold BN constants: s = g/sqrt(v+eps), t = b*s + be - m*s ----
// cst layout: s1[256] t1[256] sg[512] tg[512] s2[256] t2[256]
__global__ void prep_consts_k(const float* b1,const float* g1,const float* be1,const float* m1,const float* v1,
                              const float* bg,const float* gg,const float* beg,const float* mg,const float* vg,
                              const float* b2,const float* g2,const float* be2,const float* m2,const float* v2,
                              float* cst){
  int i = threadIdx.x;
  if (i < 256) {
    float s = g1[i]*rsqrtf(v1[i]+EPS);
    cst[i] = s; cst[256+i] = b1[i]*s + be1[i] - m1[i]*s;
    float s2 = g2[i]*rsqrtf(v2[i]+EPS);
    cst[1536+i] = s2; cst[1792+i] = b2[i]*s2 + be2[i] - m2[i]*s2;
  }
  float s = gg[i]*rsqrtf(vg[i]+EPS);
  cst[512+i] = s; cst[1024+i] = bg[i]*s + beg[i] - mg[i]*s;
}

__global__ void conv_w_k(const float* __restrict__ w1,const float* __restrict__ wg,const float* __restrict__ w2,
                         u16* __restrict__ w1b,u16* __restrict__ wgb,u16* __restrict__ w2b){
  int i = blockIdx.x*256 + threadIdx.x;
  if (i < 65536)  w1b[i] = f2b(w1[i]);
  if (i < 262144) wgb[i] = f2b(wg[i]);
  if (i < 131072) w2b[i] = f2b(w2[i]);
}

// x [b][c][s] fp32 -> xt [b][s][c] bf16
__global__ void transpose_x_k(const float* __restrict__ x, u16* __restrict__ xt){
  __shared__ float t[32][33];
  int b = blockIdx.z, ct = blockIdx.y, st = blockIdx.x;
  int ts = threadIdx.x, tc = threadIdx.y;
  #pragma unroll
  for (int i=0;i<4;i++){
    int c = tc + i*8;
    t[c][ts] = x[((size_t)(b*256 + ct*32 + c))*SPB + st*32 + ts];
  }
  __syncthreads();
  #pragma unroll
  for (int i=0;i<4;i++){
    int r = tc + i*8;
    xt[((size_t)(b*SPB + st*32 + r))*256 + ct*32 + ts] = f2b(t[ts][r]);
  }
}

// per (b,y): min over x of h, split by x-parity.  h = cat[...,0:256]
__global__ void rowmin_k(const u16* __restrict__ cat, float* __restrict__ rmin){
  int b = blockIdx.x/56, y = blockIdx.x%56, c = threadIdx.x;
  float mE=3.4e38f, mO=3.4e38f;
  const u16* base = cat + ((size_t)(b*SPB + y*56))*512 + c;
  for (int x=0;x<56;x+=2){
    mE = fminf(mE, b2f(base[(size_t)x*512]));
    mO = fminf(mO, b2f(base[(size_t)(x+1)*512]));
  }
  rmin[((size_t)(b*2+0)*56 + y)*256 + c]=mE;
  rmin[((size_t)(b*2+1)*56 + y)*256 + c]=mO;
}
// per (b,x): min over y of h, split by y-parity
__global__ void colmin_k(const u16* __restrict__ cat, float* __restrict__ cmin){
  int b = blockIdx.x/56, x = blockIdx.x%56, c = threadIdx.x;
  float mE=3.4e38f, mO=3.4e38f;
  const u16* base = cat + ((size_t)(b*SPB + x))*512 + c;
  for (int y=0;y<56;y+=2){
    mE = fminf(mE, b2f(base[(size_t)(y*56)*512]));
    mO = fminf(mO, b2f(base[(size_t)((y+1)*56)*512]));
  }
  cmin[((size_t)(b*2+0)*56 + x)*256 + c]=mE;
  cmin[((size_t)(b*2+1)*56 + x)*256 + c]=mO;
}
// xj = max(0, h - min(colMinP[y%2][x], rowMinP[x%2][y])) -> cat[...,256:512]
// coarsened: 8 spatial positions per block, short8/float4 vector accesses
__global__ __launch_bounds__(256) void xj_k(u16* __restrict__ cat, const float* __restrict__ rmin, const float* __restrict__ cmin){
  int b = blockIdx.y;
  int t = threadIdx.x;
  int s = blockIdx.x*8 + (t>>5);
  int c0 = (t&31)*8;
  int y = s/56, x = s%56;
  size_t idx = ((size_t)(b*SPB + s))*512;
  short8 h8 = *(const short8*)&cat[idx + c0];
  const float* cp = &cmin[((size_t)(b*2+(y&1))*56 + x)*256 + c0];
  const float* rp = &rmin[((size_t)(b*2+(x&1))*56 + y)*256 + c0];
  float4v cv0 = *(const float4v*)cp, cv1 = *(const float4v*)(cp+4);
  float4v rv0 = *(const float4v*)rp, rv1 = *(const float4v*)(rp+4);
  short8 o;
  #pragma unroll
  for (int j=0;j<8;j++){
    float cm = (j<4) ? cv0[j] : cv1[j-4];
    float rm = (j<4) ? rv0[j] : rv1[j-4];
    o[j] = (short)f2b(fmaxf(0.0f, b2f((u16)h8[j]) - fminf(cm, rm)));
  }
  *(short8*)&cat[idx + 256 + c0] = o;
}

// GEMM: D[m][o] = sum_k Ain[m][k] * Wt[o][k]; M flattened over batch.
// Tiles BM=128(m) x BN=128(o) x BK=32; 4 waves, each 64x64 (4x4 MFMA tiles).
// T4 counted-vmcnt pipeline, depth 2, 3 LDS buffers. Per iter:
//   sched_barrier(0)                      // pin: MFMAs + lgkm waits cannot sink
//   s_waitcnt vmcnt(4) lgkmcnt(0)         // oldest stage landed; ALL my ds_reads drained
//   s_barrier
//   sched_barrier(0)                      // pin: nothing hoists above barrier
//   STAGE(t+2)  -> buf (t+2)%3 == (t-1)%3 // safe: all reads of that buf drained pre-barrier
//   COMPUTE(t)  -> reads buf t%3
// lgkmcnt(0) BEFORE the barrier is REQUIRED: STAGE(t+2) overwrites the buffer
// COMPUTE(t-1) read; without draining, a sunk MFMA's outstanding ds_read could
// cross the barrier and race the incoming global_load_lds writes (round-2 bug).
// vmcnt stays counted (4): STAGE(t+1)'s loads remain in flight across the
// barrier -- load latency spans 2 iterations of compute (T4).
// LDS: 3 x (As 8KB + Bs 8KB) = 48KB; epilogue unions fit.
// EPI 1: bf16( acc*s + t )              -> out [m][512] at col o0
// EPI 2: bf16( gelu(acc*s + t) )        -> out [m][512] at col o0
// EPI 3: fp32( acc*s + t + x[b][o][s] ) -> out [b][256][s]
template<int KTOT, int EPI>
__global__ __launch_bounds__(256) void gemm_k(
    const u16* __restrict__ Ain, const u16* __restrict__ Wt,
    const float* __restrict__ scale, const float* __restrict__ bias,
    void* __restrict__ outp, const float* __restrict__ resid)
{
  __shared__ __align__(16) u16 smem[24576];   // 49152 B: 3 staging bufs / epilogue union
  const int tid = threadIdx.x;
  const int m0 = blockIdx.x * 128;
  const int o0 = blockIdx.y * 128;
  const int lane = tid & 63, wid = tid >> 6;
  const int quad = lane >> 4, l16 = lane & 15;
  const int wm = wid & 1, wn = wid >> 1;

  float4v acc[4][4];
  #pragma unroll
  for (int i=0;i<4;i++)
    #pragma unroll
    for (int j=0;j<4;j++) acc[i][j] = (float4v){0.f,0.f,0.f,0.f};

  // staging: buffer buf at smem + buf*8192 (u16 units):
  //   As [128][32] at +0, Bs [128][32] at +4096.
  // chunk c in [0,512): row=c>>2, q=c&3; thread t handles chunks t and 256+t
  const int row = tid >> 2, q8 = (tid & 3) * 8;
  const u16* ga0 = Ain + ((size_t)(m0 + row))*KTOT + q8;
  const u16* ga1 = ga0 + (size_t)64*KTOT;
  const u16* gb0 = Wt  + ((size_t)(o0 + row))*KTOT + q8;
  const u16* gb1 = gb0 + (size_t)64*KTOT;
  u16* l8 = smem + tid*8;

  auto STAGE = [&](int kt, int buf){
    u16* b_ = l8 + buf*8192;
    gll16(ga0 + kt, b_);
    gll16(ga1 + kt, b_ + 2048);
    gll16(gb0 + kt, b_ + 4096);
    gll16(gb1 + kt, b_ + 6144);
  };
  auto COMPUTE = [&](int buf){
    const u16* A_ = smem + buf*8192;
    const u16* B_ = A_ + 4096;
    short8 af[4], bfr[4];
    #pragma unroll
    for (int im=0;im<4;im++) af[im]  = *(const short8*)&A_[(wm*64+im*16+l16)*32 + quad*8];
    #pragma unroll
    for (int in=0;in<4;in++) bfr[in] = *(const short8*)&B_[(wn*64+in*16+l16)*32 + quad*8];
    #pragma unroll
    for (int im=0;im<4;im++)
      #pragma unroll
      for (int in=0;in<4;in++)
        acc[im][in] = __builtin_amdgcn_mfma_f32_16x16x32_bf16(af[im], bfr[in], acc[im][in], 0, 0, 0);
  };

  constexpr int NIT = KTOT / 32;
  STAGE(0, 0);
  STAGE(32, 1);
  #pragma unroll
  for (int t = 0; t < NIT; ++t) {
    __builtin_amdgcn_sched_barrier(0);
    if (t + 1 < NIT) asm volatile("s_waitcnt vmcnt(4) lgkmcnt(0)" ::: "memory");
    else             asm volatile("s_waitcnt vmcnt(0) lgkmcnt(0)" ::: "memory");
    __builtin_amdgcn_s_barrier();
    __builtin_amdgcn_sched_barrier(0);
    if (t + 2 < NIT) STAGE((t+2)*32, (t+2)%3);
    COMPUTE(t%3);
  }
  __syncthreads();            // all waves done with staging buffers -> smem reuse ok

  if (EPI == 1 || EPI == 2) {
    u16* tile = smem; // [128 m][128 o]
    #pragma unroll
    for (int im=0;im<4;im++)
      #pragma unroll
      for (int in=0;in<4;in++){
        int ol = wn*64 + in*16 + l16;
        float sc = scale[o0+ol], bi = bias[o0+ol];
        #pragma unroll
        for (int r=0;r<4;r++){
          float v = acc[im][in][r]*sc + bi;
          if (EPI==2) v = gelu_f(v);
          tile[(wm*64+im*16+quad*4+r)*128 + ol] = f2b(v);
        }
      }
    __syncthreads();
    u16* op = (u16*)outp;
    #pragma unroll
    for (int p=0;p<8;p++){
      int chunk = p*256 + tid;
      int rr = chunk >> 4, off = (chunk & 15)*8;
      *(uint4*)&op[((size_t)(m0 + rr))*512 + o0 + off] = *(const uint4*)&tile[rr*128 + off];
    }
  } else {
    float* ftile = (float*)smem; // [64 o][132 m] padded, one 64-chan half at a time
    float* op = (float*)outp;
    #pragma unroll
    for (int h=0; h<2; h++){
      if (wn == h){
        #pragma unroll
        for (int im=0;im<4;im++)
          #pragma unroll
          for (int in=0;in<4;in++){
            int c64 = in*16 + l16;
            int og = o0 + h*64 + c64;
            float sc = scale[og], bi = bias[og];
            float4v v;
            #pragma unroll
            for (int r=0;r<4;r++) v[r] = acc[im][in][r]*sc + bi;
            *(float4v*)&ftile[c64*132 + wm*64 + im*16 + quad*4] = v;
          }
      }
      __syncthreads();
      #pragma unroll
      for (int p=0;p<8;p++){
        int chunk = p*256 + tid;
        int rr = chunk >> 5, off = (chunk & 31)*4;
        int m = m0 + off;
        int b = m / SPB, s = m - b*SPB;
        size_t g = ((size_t)(b*256 + o0 + h*64 + rr))*SPB + s;
        float4v v = *(const float4v*)&ftile[rr*132 + off];
        v.x += resid[g]; v.y += resid[g+1]; v.z += resid[g+2]; v.w += resid[g+3];
        *(float4v*)&op[g] = v;
      }
      __syncthreads();
    }
  }
}

extern "C" void kernel_launch(void* const* d_in, const int* in_sizes, int n_in,
                              void* d_out, int out_size, void* d_ws, size_t ws_size,
                              hipStream_t stream)
{
  const float* x  = (const float*)d_in[0];
  const float* w1 = (const float*)d_in[1];
  const float* b1 = (const float*)d_in[2];
  const float* g1 = (const float*)d_in[3];
  const float* be1= (const float*)d_in[4];
  const float* m1 = (const float*)d_in[5];
  const float* v1 = (const float*)d_in[6];
  const float* wg = (const float*)d_in[7];
  const float* bg = (const float*)d_in[8];
  const float* gg = (const float*)d_in[9];
  const float* beg= (const float*)d_in[10];
  const float* mg = (const float*)d_in[11];
  const float* vg = (const float*)d_in[12];
  const float* w2 = (const float*)d_in[13];
  const float* b2 = (const float*)d_in[14];
  const float* g2 = (const float*)d_in[15];
  const float* be2= (const float*)d_in[16];
  const float* m2 = (const float*)d_in[17];
  const float* v2 = (const float*)d_in[18];

  char* ws = (char*)d_ws;
  size_t off = 0;
  auto alloc = [&](size_t bytes){ void* p = ws + off; off += (bytes + 255) & ~(size_t)255; return p; };
  u16* xt    = (u16*)alloc((size_t)MTOT*256*2);   // x transposed, bf16
  u16* catt  = (u16*)alloc((size_t)MTOT*512*2);   // [h ; xj] transposed, bf16
  u16* gt    = (u16*)alloc((size_t)MTOT*512*2);   // gelu output transposed, bf16
  u16* w1b   = (u16*)alloc((size_t)65536*2);
  u16* wgb   = (u16*)alloc((size_t)262144*2);
  u16* w2b   = (u16*)alloc((size_t)131072*2);
  float* cst = (float*)alloc((size_t)2048*4);
  float* rmin= (float*)alloc((size_t)NB*2*56*256*4);
  float* cmin= (float*)alloc((size_t)NB*2*56*256*4);

  hipLaunchKernelGGL(prep_consts_k, dim3(1), dim3(512), 0, stream,
                     b1,g1,be1,m1,v1, bg,gg,beg,mg,vg, b2,g2,be2,m2,v2, cst);
  hipLaunchKernelGGL(conv_w_k, dim3(1024), dim3(256), 0, stream, w1,wg,w2, w1b,wgb,w2b);
  hipLaunchKernelGGL(transpose_x_k, dim3(98,8,8), dim3(32,8), 0, stream, x, xt);
  hipLaunchKernelGGL((gemm_k<256,1>), dim3(196,2), dim3(256), 0, stream,
                     xt, w1b, cst+0, cst+256, (void*)catt, (const float*)nullptr);
  hipLaunchKernelGGL(rowmin_k, dim3(NB*56), dim3(256), 0, stream, catt, rmin);
  hipLaunchKernelGGL(colmin_k, dim3(NB*56), dim3(256), 0, stream, catt, cmin);
  hipLaunchKernelGGL(xj_k, dim3(392, NB), dim3(256), 0, stream, catt, rmin, cmin);
  hipLaunchKernelGGL((gemm_k<512,2>), dim3(196,4), dim3(256), 0, stream,
                     catt, wgb, cst+512, cst+1024, (void*)gt, (const float*)nullptr);
  hipLaunchKernelGGL((gemm_k<512,3>), dim3(196,2), dim3(256), 0, stream,
                     gt, w2b, cst+1536, cst+1792, d_out, x);
}